// Round 3
// baseline (30.916 us; speedup 1.0000x reference)
//
#include <hip/hip_runtime.h>

#define NPOS 1024
#define NBATCH 64
#define DROW 2050
#define T 8      // 128-tiles per chain
#define TS 128   // tile size
#define NTP 36   // triangular tile pairs
#define NPG 18   // pair-groups per batch (2 pairs per 256-thread block)

// One fused kernel: per block, rebuild the batch's 1024 pre-scaled positions in
// LDS (cheap, ~1us device-wide across all 18 recomputes/batch), then sweep two
// 128x128 triangular tile-pairs (waves 0-1 -> pair 2g, waves 2-3 -> pair 2g+1),
// block-reduce, one atomicAdd per block.
// pos = ALPHA*(init+cumsum), ALPHA = sqrt(4*log2 e), so e(-4 d2) == exp2(-|dp|^2).
__global__ __launch_bounds__(256) void fused_kernel(const float* __restrict__ conf,
                                                    float* __restrict__ out) {
  __shared__ float4 P[NPOS];   // 16 KB positions
  __shared__ float wx[4], wy[4], wz[4];
  __shared__ float red[4];

  const int g = blockIdx.x % NPG;
  const int b = blockIdx.x / NPG;
  const int tid = threadIdx.x;
  const int lane = tid & 63, w = tid >> 6;
  const float* __restrict__ row = conf + b * DROW;
  const float ALPHA = 2.40224481f;  // sqrt(5.770780163555856)

  // ---- phase 1: chain scan -> LDS positions ----
  float lx[4], ly[4], lz[4];
  float rx = 0.f, ry = 0.f, rz = 0.f;
#pragma unroll
  for (int k = 0; k < 4; ++k) {
    const int n = 4 * tid + k;
    if (n > 0) {
      // step m=n-1 params at row[4+2m] = row[2+2n] (8B-aligned float2)
      const float2 rr = *reinterpret_cast<const float2*>(row + 2 + 2 * n);
      const float r1 = rr.x + 0.5f;
      const float r2 = rr.y + 0.5f;
      const float ct = 1.f - 2.f * r2;                    // cos(theta)
      const float st = sqrtf(fmaxf(0.f, 1.f - ct * ct));  // sin(theta)
      const float sp = __builtin_amdgcn_sinf(r1);         // sin(2*pi*r1), hw rev input
      const float cp = __builtin_amdgcn_cosf(r1);
      rx += st * cp; ry += st * sp; rz += ct;
    }
    lx[k] = rx; ly[k] = ry; lz[k] = rz;
  }
  // wave-inclusive scan of per-thread totals
  const float tx = rx, ty = ry, tz = rz;
  float sx = rx, sy = ry, sz = rz;
#pragma unroll
  for (int off = 1; off < 64; off <<= 1) {
    const float ax = __shfl_up(sx, off, 64);
    const float ay = __shfl_up(sy, off, 64);
    const float az = __shfl_up(sz, off, 64);
    if (lane >= off) { sx += ax; sy += ay; sz += az; }
  }
  if (lane == 63) { wx[w] = sx; wy[w] = sy; wz[w] = sz; }
  __syncthreads();
  float cx = 0.f, cy = 0.f, cz = 0.f;
#pragma unroll
  for (int ww = 0; ww < 3; ++ww)
    if (ww < w) { cx += wx[ww]; cy += wy[ww]; cz += wz[ww]; }

  const float ox = row[1] + cx + (sx - tx);  // init + exclusive prefix
  const float oy = row[2] + cy + (sy - ty);
  const float oz = row[3] + cz + (sz - tz);
#pragma unroll
  for (int k = 0; k < 4; ++k) {
    P[4 * tid + k] = make_float4(ALPHA * (ox + lx[k]), ALPHA * (oy + ly[k]),
                                 ALPHA * (oz + lz[k]), 0.f);
  }
  __syncthreads();

  // ---- phase 2: two triangular tile-pairs per block (one per wave-pair) ----
  const int sub = tid >> 7;      // wave-uniform
  const int t2 = tid & 127;
  const int p = 2 * g + sub;
  int ti = 0, rem = p;
  while (rem >= T - ti) { rem -= T - ti; ++ti; }
  const int tj = ti + rem;

  const float4 pi = P[ti * TS + t2];
  const float4* __restrict__ PJ = &P[tj * TS];

  float a0 = 0.f, a1 = 0.f, a2 = 0.f, a3 = 0.f;
  if (ti != tj) {
#pragma unroll 4
    for (int jj = 0; jj < TS; jj += 4) {
      const float4 q0 = PJ[jj + 0];
      const float4 q1 = PJ[jj + 1];
      const float4 q2 = PJ[jj + 2];
      const float4 q3 = PJ[jj + 3];
      float dx, dy, dz, d2;
      dx = pi.x - q0.x; dy = pi.y - q0.y; dz = pi.z - q0.z;
      d2 = dx * dx + dy * dy + dz * dz; a0 += __builtin_amdgcn_exp2f(-d2);
      dx = pi.x - q1.x; dy = pi.y - q1.y; dz = pi.z - q1.z;
      d2 = dx * dx + dy * dy + dz * dz; a1 += __builtin_amdgcn_exp2f(-d2);
      dx = pi.x - q2.x; dy = pi.y - q2.y; dz = pi.z - q2.z;
      d2 = dx * dx + dy * dy + dz * dz; a2 += __builtin_amdgcn_exp2f(-d2);
      dx = pi.x - q3.x; dy = pi.y - q3.y; dz = pi.z - q3.z;
      d2 = dx * dx + dy * dy + dz * dz; a3 += __builtin_amdgcn_exp2f(-d2);
    }
  } else {
#pragma unroll 4
    for (int jj = 0; jj < TS; jj += 4) {
      const float4 q0 = PJ[jj + 0];
      const float4 q1 = PJ[jj + 1];
      const float4 q2 = PJ[jj + 2];
      const float4 q3 = PJ[jj + 3];
      float dx, dy, dz, d2;
      dx = pi.x - q0.x; dy = pi.y - q0.y; dz = pi.z - q0.z;
      d2 = dx * dx + dy * dy + dz * dz;
      a0 += (jj + 0 > t2) ? __builtin_amdgcn_exp2f(-d2) : 0.f;
      dx = pi.x - q1.x; dy = pi.y - q1.y; dz = pi.z - q1.z;
      d2 = dx * dx + dy * dy + dz * dz;
      a1 += (jj + 1 > t2) ? __builtin_amdgcn_exp2f(-d2) : 0.f;
      dx = pi.x - q2.x; dy = pi.y - q2.y; dz = pi.z - q2.z;
      d2 = dx * dx + dy * dy + dz * dz;
      a2 += (jj + 2 > t2) ? __builtin_amdgcn_exp2f(-d2) : 0.f;
      dx = pi.x - q3.x; dy = pi.y - q3.y; dz = pi.z - q3.z;
      d2 = dx * dx + dy * dy + dz * dz;
      a3 += (jj + 3 > t2) ? __builtin_amdgcn_exp2f(-d2) : 0.f;
    }
  }

  // ---- block reduce + one atomic ----
  float acc = (a0 + a1) + (a2 + a3);
#pragma unroll
  for (int off = 32; off; off >>= 1) acc += __shfl_down(acc, off, 64);
  if (lane == 0) red[w] = acc;
  __syncthreads();
  if (tid == 0)
    atomicAdd(out, 20.0f * ((red[0] + red[1]) + (red[2] + red[3])));  // 2*SIGMA
}

extern "C" void kernel_launch(void* const* d_in, const int* in_sizes, int n_in,
                              void* d_out, int out_size, void* d_ws, size_t ws_size,
                              hipStream_t stream) {
  const float* conf = (const float*)d_in[0];
  float* out = (float*)d_out;
  hipMemsetAsync(out, 0, sizeof(float) * out_size, stream);
  hipLaunchKernelGGL(fused_kernel, dim3(NBATCH * NPG), dim3(256), 0, stream, conf, out);
}

// Round 4
// 22.591 us; speedup vs baseline: 1.3685x; 1.3685x over previous
//
#include <hip/hip_runtime.h>

#define NPOS 1024
#define NBATCH 64
#define DROW 2050
#define T 8      // 128-tiles per chain
#define TS 128   // tile size
#define NPG 18   // groups per batch: g<4 -> 2 diagonal tiles, g>=4 -> 2 off-diag pairs
#define NBLK (NBATCH * NPG)

// Fused: per block, rebuild the batch's 1024 pre-scaled positions in LDS via a
// shuffle block-scan, then sweep two 128x128 tile-pairs (waves 0-1 -> sub 0,
// waves 2-3 -> sub 1). Diagonal tiles use circular pairing (j=(i+jj)&127,
// jj=1..63 full + jj=64 masked to i<64) so each unordered pair is hit once.
// Positions pre-scaled by ALPHA = sqrt(4*log2 e) so exp(-4 d2) == exp2(-|dp|^2).
// Per-block partial written non-atomically; reduce_kernel sums them.
__global__ __launch_bounds__(256) void fused_kernel(const float* __restrict__ conf,
                                                    float* __restrict__ part) {
  __shared__ float4 P[NPOS];   // 16 KB positions
  __shared__ float wx[4], wy[4], wz[4];
  __shared__ float red[4];

  const int g = blockIdx.x % NPG;
  const int b = blockIdx.x / NPG;
  const int tid = threadIdx.x;
  const int lane = tid & 63, w = tid >> 6;
  const float* __restrict__ row = conf + b * DROW;
  const float ALPHA = 2.40224481f;  // sqrt(5.770780163555856)

  // ---- phase 1: chain scan -> LDS positions ----
  float lx[4], ly[4], lz[4];
  float rx = 0.f, ry = 0.f, rz = 0.f;
#pragma unroll
  for (int k = 0; k < 4; ++k) {
    const int n = 4 * tid + k;
    if (n > 0) {
      // step m=n-1 params at row[4+2m] = row[2+2n] (8B-aligned float2)
      const float2 rr = *reinterpret_cast<const float2*>(row + 2 + 2 * n);
      const float r1 = rr.x + 0.5f;
      const float r2 = rr.y + 0.5f;
      const float ct = 1.f - 2.f * r2;                    // cos(theta)
      const float st = sqrtf(fmaxf(0.f, 1.f - ct * ct));  // sin(theta)
      const float sp = __builtin_amdgcn_sinf(r1);         // sin(2*pi*r1), hw rev input
      const float cp = __builtin_amdgcn_cosf(r1);
      rx += st * cp; ry += st * sp; rz += ct;
    }
    lx[k] = rx; ly[k] = ry; lz[k] = rz;
  }
  const float tx = rx, ty = ry, tz = rz;
  float sx = rx, sy = ry, sz = rz;
#pragma unroll
  for (int off = 1; off < 64; off <<= 1) {
    const float ax = __shfl_up(sx, off, 64);
    const float ay = __shfl_up(sy, off, 64);
    const float az = __shfl_up(sz, off, 64);
    if (lane >= off) { sx += ax; sy += ay; sz += az; }
  }
  if (lane == 63) { wx[w] = sx; wy[w] = sy; wz[w] = sz; }
  __syncthreads();
  float cx = 0.f, cy = 0.f, cz = 0.f;
#pragma unroll
  for (int ww = 0; ww < 3; ++ww)
    if (ww < w) { cx += wx[ww]; cy += wy[ww]; cz += wz[ww]; }

  const float ox = row[1] + cx + (sx - tx);  // init + exclusive prefix
  const float oy = row[2] + cy + (sy - ty);
  const float oz = row[3] + cz + (sz - tz);
#pragma unroll
  for (int k = 0; k < 4; ++k) {
    P[4 * tid + k] = make_float4(ALPHA * (ox + lx[k]), ALPHA * (oy + ly[k]),
                                 ALPHA * (oz + lz[k]), 0.f);
  }
  __syncthreads();

  // ---- phase 2: two tile-pairs per block, one per wave-pair ----
  const int sub = tid >> 7;  // wave-uniform
  const int t2 = tid & 127;

  float a0 = 0.f, a1 = 0.f, a2 = 0.f, a3 = 0.f;

  if (g < 4) {
    // two diagonal tiles: ti = tj = 2g + sub; circular pairing halves the work
    const int ti = 2 * g + sub;
    const float4* __restrict__ PT = &P[ti * TS];
    const float4 pi = PT[t2];
    // jj = 1..63 unmasked, 4-wide
#pragma unroll 4
    for (int jj = 1; jj <= 60; jj += 4) {
      const float4 q0 = PT[(t2 + jj + 0) & 127];
      const float4 q1 = PT[(t2 + jj + 1) & 127];
      const float4 q2 = PT[(t2 + jj + 2) & 127];
      const float4 q3 = PT[(t2 + jj + 3) & 127];
      float dx, dy, dz, d2;
      dx = pi.x - q0.x; dy = pi.y - q0.y; dz = pi.z - q0.z;
      d2 = dx * dx + dy * dy + dz * dz; a0 += __builtin_amdgcn_exp2f(-d2);
      dx = pi.x - q1.x; dy = pi.y - q1.y; dz = pi.z - q1.z;
      d2 = dx * dx + dy * dy + dz * dz; a1 += __builtin_amdgcn_exp2f(-d2);
      dx = pi.x - q2.x; dy = pi.y - q2.y; dz = pi.z - q2.z;
      d2 = dx * dx + dy * dy + dz * dz; a2 += __builtin_amdgcn_exp2f(-d2);
      dx = pi.x - q3.x; dy = pi.y - q3.y; dz = pi.z - q3.z;
      d2 = dx * dx + dy * dy + dz * dz; a3 += __builtin_amdgcn_exp2f(-d2);
    }
    // jj = 61,62,63
#pragma unroll
    for (int jj = 61; jj <= 63; ++jj) {
      const float4 q = PT[(t2 + jj) & 127];
      const float dx = pi.x - q.x, dy = pi.y - q.y, dz = pi.z - q.z;
      const float d2 = dx * dx + dy * dy + dz * dz;
      a0 += __builtin_amdgcn_exp2f(-d2);
    }
    // jj = 64: each distance-64 pair appears from both sides -> keep i<64 only
    {
      const float4 q = PT[(t2 + 64) & 127];
      const float dx = pi.x - q.x, dy = pi.y - q.y, dz = pi.z - q.z;
      const float d2 = dx * dx + dy * dy + dz * dz;
      a1 += (t2 < 64) ? __builtin_amdgcn_exp2f(-d2) : 0.f;
    }
  } else {
    // two off-diagonal pairs: q = 2*(g-4) + sub in 0..27
    int rem = 2 * (g - 4) + sub;
    int ti = 0;
    while (rem >= T - 1 - ti) { rem -= T - 1 - ti; ++ti; }
    const int tj = ti + 1 + rem;
    const float4 pi = P[ti * TS + t2];
    const float4* __restrict__ PJ = &P[tj * TS];
#pragma unroll 4
    for (int jj = 0; jj < TS; jj += 4) {
      const float4 q0 = PJ[jj + 0];
      const float4 q1 = PJ[jj + 1];
      const float4 q2 = PJ[jj + 2];
      const float4 q3 = PJ[jj + 3];
      float dx, dy, dz, d2;
      dx = pi.x - q0.x; dy = pi.y - q0.y; dz = pi.z - q0.z;
      d2 = dx * dx + dy * dy + dz * dz; a0 += __builtin_amdgcn_exp2f(-d2);
      dx = pi.x - q1.x; dy = pi.y - q1.y; dz = pi.z - q1.z;
      d2 = dx * dx + dy * dy + dz * dz; a1 += __builtin_amdgcn_exp2f(-d2);
      dx = pi.x - q2.x; dy = pi.y - q2.y; dz = pi.z - q2.z;
      d2 = dx * dx + dy * dy + dz * dz; a2 += __builtin_amdgcn_exp2f(-d2);
      dx = pi.x - q3.x; dy = pi.y - q3.y; dz = pi.z - q3.z;
      d2 = dx * dx + dy * dy + dz * dz; a3 += __builtin_amdgcn_exp2f(-d2);
    }
  }

  // ---- block reduce -> one partial per block (no atomics) ----
  float acc = (a0 + a1) + (a2 + a3);
#pragma unroll
  for (int off = 32; off; off >>= 1) acc += __shfl_down(acc, off, 64);
  if (lane == 0) red[w] = acc;
  __syncthreads();
  if (tid == 0) part[blockIdx.x] = (red[0] + red[1]) + (red[2] + red[3]);
}

__global__ __launch_bounds__(256) void reduce_kernel(const float* __restrict__ part,
                                                     float* __restrict__ out) {
  float s = 0.f;
  for (int i = threadIdx.x; i < NBLK; i += 256) s += part[i];
#pragma unroll
  for (int off = 32; off; off >>= 1) s += __shfl_down(s, off, 64);
  __shared__ float red[4];
  const int lane = threadIdx.x & 63, w = threadIdx.x >> 6;
  if (lane == 0) red[w] = s;
  __syncthreads();
  if (threadIdx.x == 0)
    out[0] = 20.0f * ((red[0] + red[1]) + (red[2] + red[3]));  // 2 * SIGMA
}

extern "C" void kernel_launch(void* const* d_in, const int* in_sizes, int n_in,
                              void* d_out, int out_size, void* d_ws, size_t ws_size,
                              hipStream_t stream) {
  const float* conf = (const float*)d_in[0];
  float* out = (float*)d_out;
  float* part = (float*)d_ws;  // NBLK floats
  hipLaunchKernelGGL(fused_kernel, dim3(NBLK), dim3(256), 0, stream, conf, part);
  hipLaunchKernelGGL(reduce_kernel, dim3(1), dim3(256), 0, stream, part, out);
}